// Round 11
// baseline (366.489 us; speedup 1.0000x reference)
//
#include <hip/hip_runtime.h>
#include <cstdint>
#include <cstddef>

// Problem constants (from reference)
#define NN 50000      // nodes
#define NE 800000     // edges
#define NP 100000     // pos/neg prediction edges each

// radix CSR build
#define EPB    3125   // edges per radix block (NE/256 exact)
#define NBUK   196    // coarse buckets: ceil(NN/256)

// prep_kernel block ranges
#define CVT_BLOCKS   12500   // NN*256/4/256
#define PACKW_BLOCKS 1024
#define RADIX1_BLOCKS 256

typedef _Float16 h8v __attribute__((ext_vector_type(8)));   // 8 f16 (4 VGPRs)
typedef _Float16 h4v __attribute__((ext_vector_type(4)));
typedef _Float16 h2v __attribute__((ext_vector_type(2)));
typedef float    f4v __attribute__((ext_vector_type(4)));

#define ATTN_SCALE 0.088388347648318447f   // 1/sqrt(128)

__device__ inline void load_lds16(const void* gptr, void* ldsptr) {
  __builtin_amdgcn_global_load_lds(
      (const __attribute__((address_space(1))) void*)gptr,
      (__attribute__((address_space(3))) void*)ldsptr, 16, 0, 0);
}

// f16x8 dot -> f32 accumulate, using v_dot2_f32_f16 when available
__device__ inline float dot8(h8v a, h8v b, float c) {
  union U { h8v v; h2v p[4]; };
  U ua; ua.v = a;
  U ub; ub.v = b;
#if __has_builtin(__builtin_amdgcn_fdot2)
  c = __builtin_amdgcn_fdot2(ua.p[0], ub.p[0], c, false);
  c = __builtin_amdgcn_fdot2(ua.p[1], ub.p[1], c, false);
  c = __builtin_amdgcn_fdot2(ua.p[2], ub.p[2], c, false);
  c = __builtin_amdgcn_fdot2(ua.p[3], ub.p[3], c, false);
#else
#pragma unroll
  for (int j = 0; j < 8; ++j) c = fmaf((float)a[j], (float)b[j], c);
#endif
  return c;
}

// ---------------------------------------------------------------------------
// prep: fused cvt(x->f16) + packw(both layers) + radix1 (coarse-bucket count)
// ---------------------------------------------------------------------------
__global__ __launch_bounds__(256) void prep_kernel(
    const float* __restrict__ x, _Float16* __restrict__ Xf,
    const float* __restrict__ Wq1, const float* __restrict__ Wk1,
    const float* __restrict__ Wv1, const float* __restrict__ Ws1,
    const float* __restrict__ Wq2, const float* __restrict__ Wk2,
    const float* __restrict__ Wv2, const float* __restrict__ Ws2,
    _Float16* __restrict__ WT1, _Float16* __restrict__ WT2,
    const int* __restrict__ dst, unsigned short* __restrict__ erank,
    int* __restrict__ blockcount) {
  __shared__ int cnt[256];
  int b = blockIdx.x;
  int tid = threadIdx.x;
  if (b < CVT_BLOCKS) {
    int i = b * 256 + tid;                    // float4 index
    float4 xv = ((const float4*)x)[i];
    h4v o = {(_Float16)xv.x, (_Float16)xv.y, (_Float16)xv.z, (_Float16)xv.w};
    ((h4v*)Xf)[i] = o;
  } else if (b < CVT_BLOCKS + PACKW_BLOCKS) {
    int bb = b - CVT_BLOCKS;
    if (bb < 512) {
      int n = bb;
      const float* W;
      switch (n >> 7) {
        case 0:  W = Wq1; break;
        case 1:  W = Wk1; break;
        case 2:  W = Wv1; break;
        default: W = Ws1; break;
      }
      WT1[(size_t)n * 256 + tid] = (_Float16)W[(size_t)tid * 128 + (n & 127)];
    } else if (tid < 128) {
      int n = bb - 512;
      const float* W;
      switch (n >> 7) {
        case 0:  W = Wq2; break;
        case 1:  W = Wk2; break;
        case 2:  W = Wv2; break;
        default: W = Ws2; break;
      }
      WT2[(size_t)n * 128 + tid] = (_Float16)W[(size_t)tid * 128 + (n & 127)];
    }
  } else {
    int blk = b - CVT_BLOCKS - PACKW_BLOCKS;  // 0..255
    cnt[tid] = 0;
    __syncthreads();
    int base = blk * EPB;
    for (int i = tid; i < EPB; i += 256) {
      int e = base + i;
      erank[e] = (unsigned short)atomicAdd(&cnt[dst[e] >> 8], 1);
    }
    __syncthreads();
    blockcount[tid * 256 + blk] = cnt[tid];
  }
}

// ---------------------------------------------------------------------------
// scan1: per-block exclusive scan + block totals (n = 65536, grid 256)
// ---------------------------------------------------------------------------
__global__ __launch_bounds__(256) void scan1_kernel(const int* __restrict__ deg,
                                                    int* __restrict__ loc,
                                                    int* __restrict__ bsum, int n) {
  __shared__ int sh[256];
  int tid = threadIdx.x;
  int i = blockIdx.x * 256 + tid;
  int val = (i < n) ? deg[i] : 0;
  sh[tid] = val;
  __syncthreads();
  for (int off = 1; off < 256; off <<= 1) {
    int add = (tid >= off) ? sh[tid - off] : 0;
    __syncthreads();
    sh[tid] += add;
    __syncthreads();
  }
  if (i < n) loc[i] = sh[tid] - val;
  if (tid == 255) bsum[blockIdx.x] = sh[255];
}

// scan23: each block sums bsum[0..bid) itself, adds to loc -> out
__global__ __launch_bounds__(256) void scan23_kernel(const int* __restrict__ loc,
                                                     const int* __restrict__ bsum,
                                                     int* __restrict__ outv,
                                                     int n, int E) {
  __shared__ int sh[256];
  int bid = blockIdx.x, tid = threadIdx.x;
  int pre = 0;
  for (int j = tid; j < bid; j += 256) pre += bsum[j];
  sh[tid] = pre;
  __syncthreads();
  for (int off = 128; off > 0; off >>= 1) {
    if (tid < off) sh[tid] += sh[tid + off];
    __syncthreads();
  }
  int base = sh[0];
  int i = bid * 256 + tid;
  if (i < n) outv[i] = loc[i] + base;
  if (bid == 0 && tid == 0) outv[n] = E;
}

// ---------------------------------------------------------------------------
// radix2: scatter edges into bucket-major tmp (u32 = src | dlo<<16).
// ---------------------------------------------------------------------------
__global__ __launch_bounds__(256) void radix2_kernel(
    const int* __restrict__ src, const int* __restrict__ dst,
    const int* __restrict__ bcscan, const unsigned short* __restrict__ erank,
    unsigned* __restrict__ tmp) {
  int blk = blockIdx.x, tid = threadIdx.x;
  int base = blk * EPB;
  for (int i = tid; i < EPB; i += 256) {
    int e = base + i;
    int d = dst[e];
    int pos = bcscan[(d >> 8) * 256 + blk] + (int)erank[e];
    tmp[pos] = (unsigned)src[e] | ((unsigned)(d & 255) << 16);
  }
}

// ---------------------------------------------------------------------------
// radix3: one block per coarse bucket -> offs + final csr_src
// ---------------------------------------------------------------------------
__global__ __launch_bounds__(256) void radix3_kernel(
    const unsigned* __restrict__ tmp, const int* __restrict__ bcscan,
    unsigned short* __restrict__ rank2,
    int* __restrict__ offs, unsigned short* __restrict__ csr_src) {
  __shared__ int cnt[256];
  __shared__ int sh[256];
  int tid = threadIdx.x, bu = blockIdx.x;
  cnt[tid] = 0;
  __syncthreads();
  int bstart = bcscan[bu * 256];
  int bend   = bcscan[(bu + 1) * 256];
  for (int i = bstart + tid; i < bend; i += 256) {
    unsigned u = tmp[i];
    rank2[i] = (unsigned short)atomicAdd(&cnt[u >> 16], 1);
  }
  __syncthreads();
  int v = cnt[tid];
  sh[tid] = v;
  __syncthreads();
  for (int off = 1; off < 256; off <<= 1) {
    int add = (tid >= off) ? sh[tid - off] : 0;
    __syncthreads();
    sh[tid] += add;
    __syncthreads();
  }
  int excl = sh[tid] - v;
  int node = bu * 256 + tid;
  if (node < NN) offs[node] = bstart + excl;
  if (bu == 0 && tid == 0) offs[NN] = NE;
  __syncthreads();
  cnt[tid] = excl;          // publish exclusive scan for the scatter loop
  __syncthreads();
  for (int i = bstart + tid; i < bend; i += 256) {
    unsigned u = tmp[i];
    csr_src[bstart + cnt[u >> 16] + (int)rank2[i]] = (unsigned short)(u & 0xffffu);
  }
}

// ---------------------------------------------------------------------------
// f16 MFMA GEMM, issue-then-compute-then-barrier A double-buffer, B from L2.
// grid (391, 4): blockIdx.y = projection p; one 128x128 tile per block.
// Block: 256 thr = 4 waves (2x2 of 64x64), BK=64.
// LDS 32 KB: As[2][128][64] (XOR-swizzled); As reused as epilogue buf [64][128].
// B fragments loaded directly global->VGPR per kk (WT is L2-resident, 256 KB).
// Key: next k-step's A staging is ISSUED right after the barrier, then compute
// runs on the current buffer — the next barrier's vmcnt(0) drain waits only on
// loads that had a full compute phase in flight (removes the m97-style stall).
// ---------------------------------------------------------------------------
__global__ __launch_bounds__(256) void gemm_l2b_kernel(
    const _Float16* __restrict__ A, int M, int K,
    const _Float16* __restrict__ BT,   // [512][K]
    const float* __restrict__ bq, const float* __restrict__ bk,
    const float* __restrict__ bv, const float* __restrict__ bs,
    _Float16* __restrict__ Oq, _Float16* __restrict__ Okv,
    _Float16* __restrict__ Os) {
  __shared__ _Float16 As[2][128 * 64];   // 32 KB

  const int tx = threadIdx.x;
  const int w = tx >> 6;
  const int lane = tx & 63;
  const int lr = lane & 15;
  const int q = lane >> 4;
  const int wm = w >> 1, wn = w & 1;
  const int p = blockIdx.y;
  const int row0 = blockIdx.x * 128;

  f4v acc[4][4];
#pragma unroll
  for (int i = 0; i < 4; ++i)
#pragma unroll
    for (int j = 0; j < 4; ++j) acc[i][j] = (f4v){0.f, 0.f, 0.f, 0.f};

  // stage A tile [128][64] (swizzled 16B chunks): 16 wave-ops, 4 per wave
#define STAGE_A(buf, kbase)                                              \
  {                                                                      \
    _Pragma("unroll")                                                    \
    for (int o = 0; o < 4; ++o) {                                        \
      int i = o * 4 + w;                                                 \
      int r = i * 8 + (lane >> 3);                                       \
      int cl = (lane & 7) ^ (r & 7);                                     \
      int gr = row0 + r;                                                 \
      if (gr > M - 1) gr = M - 1;                                        \
      load_lds16(A + (size_t)gr * K + (kbase) + cl * 8,                  \
                 &As[buf][i * 8 * 64]);                                  \
    }                                                                    \
  }

  STAGE_A(0, 0);
  int cur = 0;

  for (int k0 = 0; k0 < K; k0 += 64) {
    __syncthreads();                 // drains: As[cur] ready
    if (k0 + 64 < K) STAGE_A(cur ^ 1, k0 + 64);   // async; overlaps compute

#pragma unroll
    for (int kk = 0; kk < 2; ++kk) {
      h8v af[4], bf[4];
#pragma unroll
      for (int t = 0; t < 4; ++t) {
        int row = wm * 64 + t * 16 + lr;
        af[t] = *(const h8v*)&As[cur][row * 64 + (((kk * 4 + q) ^ (row & 7)) * 8)];
        int col = p * 128 + wn * 64 + t * 16 + lr;
        bf[t] = *(const h8v*)(BT + (size_t)col * K + k0 + kk * 32 + q * 8);
      }
#pragma unroll
      for (int mt = 0; mt < 4; ++mt)
#pragma unroll
        for (int nt = 0; nt < 4; ++nt)
          acc[mt][nt] = __builtin_amdgcn_mfma_f32_16x16x32_f16(af[mt], bf[nt],
                                                               acc[mt][nt], 0, 0, 0);
    }
    cur ^= 1;
  }
#undef STAGE_A

  // epilogue: C/D layout col=lane&15, row=(lane>>4)*4+reg; stage 64-row halves
  // in As (16 KB as [64][128]) then store coalesced f16x8.
  _Float16* Ep = &As[0][0];
  const float* bp = (p == 0) ? bq : (p == 1) ? bk : (p == 2) ? bv : bs;
#pragma unroll
  for (int half = 0; half < 2; ++half) {
    __syncthreads();
    if (wm == half) {
#pragma unroll
      for (int nt = 0; nt < 4; ++nt) {
        int col = wn * 64 + nt * 16 + lr;       // 0..127 within projection
        float bval = bp[col];
#pragma unroll
        for (int mt = 0; mt < 4; ++mt)
#pragma unroll
          for (int reg = 0; reg < 4; ++reg) {
            int r = mt * 16 + q * 4 + reg;      // local row 0..63
            Ep[r * 128 + col] = (_Float16)(acc[mt][nt][reg] + bval);
          }
      }
    }
    __syncthreads();
    // store 64x128 f16 = 1024 chunks of 8; 256 thr x 4
#pragma unroll
    for (int i = 0; i < 4; ++i) {
      int sl = i * 256 + tx;
      int rr = sl >> 4;               // 0..63
      int col = (sl & 15) * 8;
      int grow = row0 + half * 64 + rr;
      if (grow < M) {
        _Float16* dstp;
        switch (p) {
          case 0:  dstp = Oq  + (size_t)grow * 128 + col;       break;
          case 1:  dstp = Okv + (size_t)grow * 256 + col;       break;
          case 2:  dstp = Okv + (size_t)grow * 256 + 128 + col; break;
          default: dstp = Os  + (size_t)grow * 128 + col;       break;
        }
        *(h8v*)dstp = *(const h8v*)&Ep[rr * 128 + col];
      }
    }
  }
}

// ---------------------------------------------------------------------------
// Single-pass fused attention with index-prefetch pipeline.
// One wave per dst node; 4 edge-groups x 16 lanes (x8 channels).
// k,v interleaved in kv[node][256]; u16 csr; 2 edges per group in flight.
// ---------------------------------------------------------------------------
__global__ __launch_bounds__(256) void attn_fused_kernel(
    const _Float16* __restrict__ qf, const _Float16* __restrict__ kvf,
    const _Float16* __restrict__ sf,
    const int* __restrict__ offs, const unsigned short* __restrict__ csr_src,
    _Float16* __restrict__ hf, int n_nodes, int do_relu) {
  int node = (int)((blockIdx.x * 256u + threadIdx.x) >> 6);
  if (node >= n_nodes) return;
  int lane = threadIdx.x & 63;
  int g = lane >> 4;        // edge group 0..3
  int t = lane & 15;        // channel chunk: channels t*8 .. t*8+7

  h8v qv = *(const h8v*)(qf + (size_t)node * 128 + t * 8);
  int beg = offs[node], end = offs[node + 1];

  float den = 0.f;
  float acc[8];
#pragma unroll
  for (int j = 0; j < 8; ++j) acc[j] = 0.f;

  int e = beg + g;
  int sn0 = 0, sn1 = 0;
  if (e < end) sn0 = csr_src[e];
  if (e + 4 < end) sn1 = csr_src[e + 4];

  for (; e + 4 < end; e += 8) {           // 2 edges per group in flight
    const _Float16* r0 = kvf + (size_t)sn0 * 256 + t * 8;
    const _Float16* r1 = kvf + (size_t)sn1 * 256 + t * 8;
    h8v k0 = *(const h8v*)r0, v0 = *(const h8v*)(r0 + 128);
    h8v k1 = *(const h8v*)r1, v1 = *(const h8v*)(r1 + 128);
    // prefetch next pair of indices (breaks the index->kv chase chain)
    int nn0 = (e + 8  < end) ? (int)csr_src[e + 8]  : 0;
    int nn1 = (e + 12 < end) ? (int)csr_src[e + 12] : 0;
    float p0 = dot8(qv, k0, 0.f);
    float p1 = dot8(qv, k1, 0.f);
    p0 += __shfl_xor(p0, 1); p1 += __shfl_xor(p1, 1);
    p0 += __shfl_xor(p0, 2); p1 += __shfl_xor(p1, 2);
    p0 += __shfl_xor(p0, 4); p1 += __shfl_xor(p1, 4);
    p0 += __shfl_xor(p0, 8); p1 += __shfl_xor(p1, 8);
    float w0 = __expf(p0 * ATTN_SCALE);
    float w1 = __expf(p1 * ATTN_SCALE);
    den += w0 + w1;
#pragma unroll
    for (int j = 0; j < 8; ++j) {
      acc[j] = fmaf(w0, (float)v0[j], acc[j]);
      acc[j] = fmaf(w1, (float)v1[j], acc[j]);
    }
    sn0 = nn0; sn1 = nn1;
  }
  if (e < end) {                           // leftover: sn0 already prefetched
    const _Float16* r0 = kvf + (size_t)sn0 * 256 + t * 8;
    h8v k0 = *(const h8v*)r0, v0 = *(const h8v*)(r0 + 128);
    float p0 = dot8(qv, k0, 0.f);
    p0 += __shfl_xor(p0, 1);
    p0 += __shfl_xor(p0, 2);
    p0 += __shfl_xor(p0, 4);
    p0 += __shfl_xor(p0, 8);
    float w0 = __expf(p0 * ATTN_SCALE);
    den += w0;
#pragma unroll
    for (int j = 0; j < 8; ++j) acc[j] = fmaf(w0, (float)v0[j], acc[j]);
  }

  // merge the 4 edge-groups (each lane keeps channels t*8..t*8+7)
#pragma unroll
  for (int j = 0; j < 8; ++j) {
    acc[j] += __shfl_xor(acc[j], 16);
    acc[j] += __shfl_xor(acc[j], 32);
  }
  den += __shfl_xor(den, 16);
  den += __shfl_xor(den, 32);

  if (g == 0) {
    float inv = (end > beg) ? 1.f / den : 0.f;
    h8v sk = *(const h8v*)(sf + (size_t)node * 128 + t * 8);
    h8v of;
#pragma unroll
    for (int j = 0; j < 8; ++j) {
      float o = fmaf(acc[j], inv, (float)sk[j]);
      if (do_relu) o = fmaxf(o, 0.f);
      of[j] = (_Float16)o;
    }
    *(h8v*)(hf + (size_t)node * 128 + t * 8) = of;
  }
}

// ---------------------------------------------------------------------------
// Edge scorer: 16 lanes per prediction edge (4 edges/wave), f16 h.
// ---------------------------------------------------------------------------
__global__ __launch_bounds__(256) void scorer_kernel(
    const _Float16* __restrict__ hf,
    const int* __restrict__ pos0, const int* __restrict__ pos1,
    const int* __restrict__ neg0, const int* __restrict__ neg1,
    const float* __restrict__ Wl, const float* __restrict__ bl,
    float* __restrict__ out, int npred) {
  int eid = (int)((blockIdx.x * 256u + threadIdx.x) >> 4);
  if (eid >= 2 * npred) return;
  int t = threadIdx.x & 15;

  int a, b;
  if (eid < npred) { a = pos0[eid]; b = pos1[eid]; }
  else             { a = neg0[eid - npred]; b = neg1[eid - npred]; }

  h8v ha = *(const h8v*)(hf + (size_t)a * 128 + t * 8);
  h8v hb = *(const h8v*)(hf + (size_t)b * 128 + t * 8);
  const float4* wp = (const float4*)(Wl + t * 8);
  float4 w0 = wp[0], w1 = wp[1];
  float wl[8] = {w0.x, w0.y, w0.z, w0.w, w1.x, w1.y, w1.z, w1.w};
  float p = 0.f;
#pragma unroll
  for (int j = 0; j < 8; ++j)
    p = fmaf((float)ha[j] * (float)hb[j], wl[j], p);
  p += __shfl_xor(p, 1);
  p += __shfl_xor(p, 2);
  p += __shfl_xor(p, 4);
  p += __shfl_xor(p, 8);
  if (t == 0) out[eid] = p + bl[0];
}

// ---------------------------------------------------------------------------
extern "C" void kernel_launch(void* const* d_in, const int* in_sizes, int n_in,
                              void* d_out, int out_size, void* d_ws, size_t ws_size,
                              hipStream_t stream) {
  const float* x   = (const float*)d_in[0];
  const int*   ei  = (const int*)d_in[1];
  const int*   pos = (const int*)d_in[2];
  const int*   neg = (const int*)d_in[3];
  const float* Wq1 = (const float*)d_in[4];  const float* bq1 = (const float*)d_in[5];
  const float* Wk1 = (const float*)d_in[6];  const float* bk1 = (const float*)d_in[7];
  const float* Wv1 = (const float*)d_in[8];  const float* bv1 = (const float*)d_in[9];
  const float* Ws1 = (const float*)d_in[10]; const float* bs1 = (const float*)d_in[11];
  const float* Wq2 = (const float*)d_in[12]; const float* bq2 = (const float*)d_in[13];
  const float* Wk2 = (const float*)d_in[14]; const float* bk2 = (const float*)d_in[15];
  const float* Wv2 = (const float*)d_in[16]; const float* bv2 = (const float*)d_in[17];
  const float* Ws2 = (const float*)d_in[18]; const float* bs2 = (const float*)d_in[19];
  const float* Wl  = (const float*)d_in[20]; const float* bl  = (const float*)d_in[21];
  float* out = (float*)d_out;

  // ---- workspace carve ----
  const size_t NODE_C = (size_t)NN * 128;
  char* p = (char*)d_ws;
  _Float16* qf  = (_Float16*)p; p += NODE_C * 2;              // 12.8 MB
  _Float16* kvf = (_Float16*)p; p += NODE_C * 4;              // 25.6 MB (k|v)
  _Float16* sf  = (_Float16*)p; p += NODE_C * 2;
  _Float16* h1  = (_Float16*)p; p += NODE_C * 2;
  _Float16* h2  = (_Float16*)p; p += NODE_C * 2;
  _Float16* Xf  = (_Float16*)p; p += (size_t)NN * 256 * 2;    // 25.6 MB
  _Float16* WT1 = (_Float16*)p; p += 512 * 256 * 2;
  _Float16* WT2 = (_Float16*)p; p += 512 * 128 * 2;
  unsigned short* erank = (unsigned short*)p; p += (size_t)NE * 2;
  unsigned short* rank2 = (unsigned short*)p; p += (size_t)NE * 2;
  unsigned* tmp = (unsigned*)p;  p += (size_t)NE * 4;
  int* bc     = (int*)p;         p += 65536 * 4;
  int* bcloc  = (int*)p;         p += 65536 * 4;
  int* bcbs   = (int*)p;         p += 256 * 4;
  int* bcscan = (int*)p;         p += 65544 * 4;   // 65537 + pad
  int* offs   = (int*)p;         p += (size_t)(NN + 8) * 4;
  unsigned short* csr_src = (unsigned short*)p; p += (size_t)NE * 2;

  const int* e_src = ei;
  const int* e_dst = ei + NE;

  // fused prep: cvt + packw + radix1 (coarse count, LDS atomics only)
  prep_kernel<<<CVT_BLOCKS + PACKW_BLOCKS + RADIX1_BLOCKS, 256, 0, stream>>>(
      x, Xf, Wq1, Wk1, Wv1, Ws1, Wq2, Wk2, Wv2, Ws2, WT1, WT2,
      e_dst, erank, bc);

  // exclusive scan of blockcount[65536] (bucket-major)
  scan1_kernel<<<256, 256, 0, stream>>>(bc, bcloc, bcbs, 65536);
  scan23_kernel<<<256, 256, 0, stream>>>(bcloc, bcbs, bcscan, 65536, NE);

  // bucket-major edge partition, then per-bucket CSR finalize
  radix2_kernel<<<256, 256, 0, stream>>>(e_src, e_dst, bcscan, erank, tmp);
  radix3_kernel<<<NBUK, 256, 0, stream>>>(tmp, bcscan, rank2, offs, csr_src);

  dim3 ggrid(391, 4);
  int attn_blocks = (NN * 64 + 255) / 256;

  // conv1: K=256
  gemm_l2b_kernel<<<ggrid, 256, 0, stream>>>(Xf, NN, 256, WT1,
                                             bq1, bk1, bv1, bs1, qf, kvf, sf);
  attn_fused_kernel<<<attn_blocks, 256, 0, stream>>>(
      qf, kvf, sf, offs, csr_src, h1, NN, 1);

  // conv2: K=128
  gemm_l2b_kernel<<<ggrid, 256, 0, stream>>>(h1, NN, 128, WT2,
                                             bq2, bk2, bv2, bs2, qf, kvf, sf);
  attn_fused_kernel<<<attn_blocks, 256, 0, stream>>>(
      qf, kvf, sf, offs, csr_src, h2, NN, 0);

  // scorer
  scorer_kernel<<<(2 * NP * 16 + 255) / 256, 256, 0, stream>>>(
      h2, pos, pos + NP, neg, neg + NP, Wl, bl, out, NP);
}